// Round 2
// baseline (1006.945 us; speedup 1.0000x reference)
//
#include <hip/hip_runtime.h>
#include <math.h>

#define D 256
#define LDS_STRIDE 40   // 32 + 8 pad shorts: 80B row stride, 16B-aligned, 2-way (free) LDS banks

typedef __attribute__((ext_vector_type(8))) short short8;
typedef __attribute__((ext_vector_type(4))) float f32x4;

__device__ inline unsigned short f2bf(float f) {
    unsigned int u = __float_as_uint(f);
    u += 0x7fff + ((u >> 16) & 1);          // RNE
    return (unsigned short)(u >> 16);
}
__device__ inline float bf2f(unsigned short h) {
    return __uint_as_float(((unsigned int)h) << 16);
}

// ---------------------------------------------------------------------------
// Fused prep: Wk fp32->bf16, Wg transpose->bf16, zero counts.
// (prev is no longer pre-converted: GEMMs stage fp32->bf16 on the fly.)
__global__ __launch_bounds__(256)
void k_prep(const float* __restrict__ Wk, const float* __restrict__ Wg,
            unsigned short* __restrict__ Wk_bf, unsigned short* __restrict__ WgT,
            int* __restrict__ counts, int nWk8, int Nn, int gWk, int gWgT) {
    int b = blockIdx.x;
    int t = threadIdx.x;
    if (b < gWk) {
        int i = b * 256 + t;
        if (i < nWk8) {
            const float4* p = (const float4*)(Wk + (size_t)i * 8);
            float4 a = p[0], c = p[1];
            ushort4 o0 = { f2bf(a.x), f2bf(a.y), f2bf(a.z), f2bf(a.w) };
            ushort4 o1 = { f2bf(c.x), f2bf(c.y), f2bf(c.z), f2bf(c.w) };
            ushort4* q = (ushort4*)(Wk_bf + (size_t)i * 8);
            q[0] = o0; q[1] = o1;
        }
    } else if (b < gWk + gWgT) {
        int r = b - gWk;                    // 0..2D-1 (k index)
        int c = t;                          // 0..D-1  (n index)
        WgT[(size_t)c * (2 * D) + r] = f2bf(Wg[(size_t)r * D + c]);
    } else {
        int i = (b - gWk - gWgT) * 256 + t;
        if (i < Nn) counts[i] = 0;
    }
}

// ---------------------------------------------------------------------------
// MFMA GEMM body: C[M][256] = A[M][K] @ B[K][256].
// A fp32 (prev) for k<256, bf16 (comb) for k>=256 (GATE). fp32->bf16 in staging.
// B n-major: Bn[n][k]. Block: 64 rows x 256 cols, 4 waves, K-step 32.
template <int K, bool GATE>
__device__ __forceinline__ void gemm_body(
        const float* __restrict__ Af,
        const unsigned short* __restrict__ A1,
        const unsigned short* __restrict__ Bn,
        const float* __restrict__ bg,
        const float* __restrict__ prevf,
        unsigned short* __restrict__ wq_out,
        float* __restrict__ outp,
        int Nrows, int blk) {
    __shared__ unsigned short As[64 * LDS_STRIDE];    // 5 KB
    __shared__ unsigned short Bs[256 * LDS_STRIDE];   // 20 KB

    int tid  = threadIdx.x;
    int wave = tid >> 6;
    int lane = tid & 63;
    int lcol = lane & 15;
    int quad = lane >> 4;
    int row0 = blk * 64;

    f32x4 acc[4][4];
    #pragma unroll
    for (int i = 0; i < 4; i++)
        #pragma unroll
        for (int j = 0; j < 4; j++) acc[i][j] = (f32x4){0.f, 0.f, 0.f, 0.f};

    int arow = tid >> 2, ako = (tid & 3) * 8;
    int grow = row0 + arow;

    for (int kk = 0; kk < K; kk += 32) {
        // ---- stage A (8 k-elems per thread) ----
        ushort4 h0 = {0, 0, 0, 0}, h1 = {0, 0, 0, 0};
        if (grow < Nrows) {
            if (!GATE || kk < 256) {
                const float* s = &Af[(size_t)grow * D + kk + ako];
                float4 f0 = *(const float4*)s;
                float4 f1 = *(const float4*)(s + 4);
                h0 = (ushort4){ f2bf(f0.x), f2bf(f0.y), f2bf(f0.z), f2bf(f0.w) };
                h1 = (ushort4){ f2bf(f1.x), f2bf(f1.y), f2bf(f1.z), f2bf(f1.w) };
            } else {
                const ushort4* s = (const ushort4*)&A1[(size_t)grow * D + (kk - 256) + ako];
                h0 = s[0]; h1 = s[1];
            }
        }
        *(ushort4*)&As[arow * LDS_STRIDE + ako]     = h0;
        *(ushort4*)&As[arow * LDS_STRIDE + ako + 4] = h1;

        // ---- stage B ----
        #pragma unroll
        for (int i = 0; i < 4; i++) {
            int c = tid + i * 256;
            int brow = c >> 2, bko = (c & 3) * 8;
            *(uint4*)&Bs[brow * LDS_STRIDE + bko] =
                *(const uint4*)&Bn[(size_t)brow * K + kk + bko];
        }
        __syncthreads();

        short8 a[4], b[4];
        #pragma unroll
        for (int mf = 0; mf < 4; mf++)
            a[mf] = *(const short8*)&As[(mf * 16 + lcol) * LDS_STRIDE + quad * 8];
        #pragma unroll
        for (int nf = 0; nf < 4; nf++)
            b[nf] = *(const short8*)&Bs[(wave * 64 + nf * 16 + lcol) * LDS_STRIDE + quad * 8];
        #pragma unroll
        for (int mf = 0; mf < 4; mf++)
            #pragma unroll
            for (int nf = 0; nf < 4; nf++)
                acc[mf][nf] = __builtin_amdgcn_mfma_f32_16x16x32_bf16(
                    a[mf], b[nf], acc[mf][nf], 0, 0, 0);
        __syncthreads();
    }

    if (!GATE) {
        #pragma unroll
        for (int mf = 0; mf < 4; mf++) {
            #pragma unroll
            for (int nf = 0; nf < 4; nf++) {
                int col = wave * 64 + nf * 16 + lcol;
                #pragma unroll
                for (int r = 0; r < 4; r++) {
                    int gr = row0 + mf * 16 + quad * 4 + r;
                    if (gr < Nrows)
                        wq_out[(size_t)gr * D + col] = f2bf(acc[mf][nf][r]);
                }
            }
        }
    } else {
        float bgv[4];
        #pragma unroll
        for (int nf = 0; nf < 4; nf++) bgv[nf] = bg[wave * 64 + nf * 16 + lcol];
        #pragma unroll
        for (int mf = 0; mf < 4; mf++) {
            #pragma unroll
            for (int nf = 0; nf < 4; nf++) {
                int col = wave * 64 + nf * 16 + lcol;
                #pragma unroll
                for (int r = 0; r < 4; r++) {
                    int gr = row0 + mf * 16 + quad * 4 + r;
                    if (gr < Nrows) {
                        size_t o = (size_t)gr * D + col;
                        float logit = acc[mf][nf][r] + bgv[nf];
                        float g = 1.f / (1.f + __expf(-logit));
                        float cb = bf2f(A1[o]);
                        outp[o] = g * prevf[o] + (1.f - g) * cb;
                    }
                }
            }
        }
    }
}

// gate GEMM + sigmoid lerp epilogue
__global__ __launch_bounds__(256)
void k_gemm_gate(const float* __restrict__ prev, const unsigned short* __restrict__ comb,
                 const unsigned short* __restrict__ WgT, const float* __restrict__ bg,
                 float* __restrict__ outp, int Nrows) {
    gemm_body<512, true>(prev, comb, WgT, bg, prev, nullptr, outp, Nrows, blockIdx.x);
}

// ---------------------------------------------------------------------------
// Counting sort of occurrence ids by node index.
__global__ __launch_bounds__(256)
void k_hist(const int* __restrict__ idx, int* __restrict__ counts,
            int* __restrict__ rank, int E_) {
    int e = blockIdx.x * 256 + threadIdx.x;
    if (e < E_) rank[e] = atomicAdd(&counts[idx[e]], 1);
}

// Single-kernel exclusive scan over counts -> offsets.
// Block b redundantly reduces counts[0 .. b*1024) from L2 (cheap, race-free),
// then scans its own 1024-element chunk. Replaces k_part + k_top + k_off.
__global__ __launch_bounds__(256)
void k_scan(const int* __restrict__ counts, int* __restrict__ offsets,
            int Nn, int E_) {
    __shared__ int sd[256];
    __shared__ int ws[4];
    int b = blockIdx.x, t = threadIdx.x, lane = t & 63, w = t >> 6;

    // 1) base = sum of all predecessor chunks
    int pre = b * 1024;
    int s = 0;
    for (int i = t; i < pre; i += 256) s += counts[i];
    sd[t] = s;
    __syncthreads();
    for (int st = 128; st; st >>= 1) {
        if (t < st) sd[t] += sd[t + st];
        __syncthreads();
    }
    int base = sd[0];

    // 2) exclusive scan of own chunk (4 elems/thread)
    int g0 = b * 1024 + t * 4;
    int c[4]; int ts = 0;
    #pragma unroll
    for (int j = 0; j < 4; j++) {
        int g = g0 + j;
        c[j] = (g < Nn) ? counts[g] : 0;
        ts += c[j];
    }
    int v = ts;
    for (int off = 1; off < 64; off <<= 1) {
        int u = __shfl_up(v, off, 64);
        if (lane >= off) v += u;
    }
    if (lane == 63) ws[w] = v;
    __syncthreads();
    int wex = 0;
    for (int k = 0; k < w; k++) wex += ws[k];
    int run = base + wex + v - ts;
    #pragma unroll
    for (int j = 0; j < 4; j++) {
        int g = g0 + j;
        if (g < Nn) offsets[g] = run;
        run += c[j];
    }
    if (b == 0 && t == 0) offsets[Nn] = E_;
}

// ---------------------------------------------------------------------------
// Fused independent stages: blocks [0,gm) run the wq GEMM (prev @ Wk^T),
// blocks [gm, gm+gSc) run the sort scatter. Both depend only on hist+scan;
// fusing overlaps a compute-bound GEMM with a latency-bound scatter.
__global__ __launch_bounds__(256)
void k_fused1(const int* __restrict__ idx, const int* __restrict__ rank,
              const int* __restrict__ offsets, int* __restrict__ perm, int E_,
              const float* __restrict__ prev, const unsigned short* __restrict__ Wk_bf,
              unsigned short* __restrict__ wq_bf, int Nrows, int gm) {
    int b = blockIdx.x;
    if (b < gm) {
        gemm_body<256, false>(prev, nullptr, Wk_bf, nullptr, nullptr, wq_bf, nullptr,
                              Nrows, b);
    } else {
        int e = (b - gm) * 256 + threadIdx.x;
        if (e < E_) perm[offsets[idx[e]] + rank[e]] = e;
    }
}

// ---------------------------------------------------------------------------
// One wave per node: online-softmax attention; 3-deep row prefetch + 1-ahead
// perm index to cover HBM latency across the reduce/exp chain.
__global__ __launch_bounds__(256)
void k_combine(const float* __restrict__ scat, const unsigned short* __restrict__ wq,
               const int* __restrict__ offsets, const int* __restrict__ perm,
               unsigned short* __restrict__ comb, int Nnodes) {
    int wave = threadIdx.x >> 6;
    int lane = threadIdx.x & 63;
    int n = blockIdx.x * 4 + wave;
    if (n >= Nnodes) return;

    ushort4 wu = *(const ushort4*)&wq[(size_t)n * D + lane * 4];
    float4 wqv = { bf2f(wu.x), bf2f(wu.y), bf2f(wu.z), bf2f(wu.w) };
    int beg = offsets[n], end = offsets[n + 1];

    float m = -INFINITY, l = 0.f;
    float4 acc = { 0.f, 0.f, 0.f, 0.f };
    const float scale = 0.0625f;   // 1/sqrt(256)

    if (beg < end) {
        float4 sv0 = *(const float4*)&scat[(size_t)perm[beg] * D + lane * 4];
        float4 sv1 = sv0, sv2 = sv0;
        if (beg + 1 < end) sv1 = *(const float4*)&scat[(size_t)perm[beg + 1] * D + lane * 4];
        if (beg + 2 < end) sv2 = *(const float4*)&scat[(size_t)perm[beg + 2] * D + lane * 4];
        int ea = (beg + 3 < end) ? perm[beg + 3] : 0;
        for (int pos = beg; pos < end; ++pos) {
            float4 cur = sv0;
            sv0 = sv1; sv1 = sv2;
            if (pos + 3 < end) {
                sv2 = *(const float4*)&scat[(size_t)ea * D + lane * 4];
                ea = (pos + 4 < end) ? perm[pos + 4] : 0;
            }
            float d = fmaf(cur.x, wqv.x, fmaf(cur.y, wqv.y,
                      fmaf(cur.z, wqv.z, cur.w * wqv.w)));
            #pragma unroll
            for (int off = 32; off; off >>= 1) d += __shfl_xor(d, off, 64);
            float score = d * scale;
            float nm = fmaxf(m, score);
            float al = __expf(m - nm);       // first iter: exp(-inf)=0
            float p  = __expf(score - nm);
            l = fmaf(l, al, p);
            acc.x = fmaf(acc.x, al, p * cur.x);
            acc.y = fmaf(acc.y, al, p * cur.y);
            acc.z = fmaf(acc.z, al, p * cur.z);
            acc.w = fmaf(acc.w, al, p * cur.w);
            m = nm;
        }
    }
    float inv = 1.f / fmaxf(l, 1e-9f);
    ushort4 o = { f2bf(acc.x * inv), f2bf(acc.y * inv),
                  f2bf(acc.z * inv), f2bf(acc.w * inv) };
    *(ushort4*)&comb[(size_t)n * D + lane * 4] = o;
}

// ---------------------------------------------------------------------------
extern "C" void kernel_launch(void* const* d_in, const int* in_sizes, int n_in,
                              void* d_out, int out_size, void* d_ws, size_t ws_size,
                              hipStream_t stream) {
    const float* scat = (const float*)d_in[0];
    const float* prev = (const float*)d_in[1];
    const float* Wk   = (const float*)d_in[2];
    // d_in[3] = b_k: constant shift within a segment cancels in softmax.
    const float* Wg   = (const float*)d_in[4];
    const float* bg   = (const float*)d_in[5];
    const int*   idx  = (const int*)d_in[6];

    const int E_ = in_sizes[6];
    const int Nn = in_sizes[1] / D;

    float* out = (float*)d_out;

    char* w = (char*)d_ws;
    auto alloc = [&](size_t bytes) -> char* {
        char* p = w;
        w += (bytes + 255) & ~(size_t)255;
        return p;
    };
    unsigned short* wq_bf   = (unsigned short*)alloc((size_t)Nn * D * 2);
    unsigned short* comb_bf = (unsigned short*)alloc((size_t)Nn * D * 2);
    unsigned short* Wk_bf   = (unsigned short*)alloc((size_t)D * D * 2);
    unsigned short* WgT_bf  = (unsigned short*)alloc((size_t)2 * D * D * 2);
    int*   counts    = (int*)alloc((size_t)Nn * 4);
    int*   offsets   = (int*)alloc(((size_t)Nn + 1) * 4);
    int*   rank      = (int*)alloc((size_t)E_ * 4);
    int*   perm      = (int*)alloc((size_t)E_ * 4);

    // 1) weight conversions + counts zero (one launch)
    int nWk8  = D * D / 8;
    int gWk   = (nWk8 + 255) / 256;
    int gWgT  = 2 * D;
    int gCnt  = (Nn + 255) / 256;
    k_prep<<<gWk + gWgT + gCnt, 256, 0, stream>>>(
        Wk, Wg, Wk_bf, WgT_bf, counts, nWk8, Nn, gWk, gWgT);

    // 2) histogram (rank per occurrence)
    int gb = (E_ + 255) / 256;
    k_hist<<<gb, 256, 0, stream>>>(idx, counts, rank, E_);

    // 3) single-kernel scan -> offsets
    int P = (Nn + 1023) / 1024;
    k_scan<<<P, 256, 0, stream>>>(counts, offsets, Nn, E_);

    // 4) fused: wq GEMM (prev @ Wk^T, fp32 staged->bf16) || sort scatter
    int gm  = (Nn + 63) / 64;
    int gSc = (E_ + 255) / 256;
    k_fused1<<<gm + gSc, 256, 0, stream>>>(
        idx, rank, offsets, perm, E_, prev, Wk_bf, wq_bf, Nn, gm);

    // 5) per-node online-softmax attention (single pass over scattered_input)
    k_combine<<<(Nn + 3) / 4, 256, 0, stream>>>(scat, wq_bf, offsets, perm, comb_bf, Nn);

    // 6) gate GEMM + sigmoid lerp epilogue
    k_gemm_gate<<<gm, 256, 0, stream>>>(prev, comb_bf, WgT_bf, bg, out, Nn);
}